// Round 3
// baseline (210.881 us; speedup 1.0000x reference)
//
#include <hip/hip_runtime.h>

#define NB 2048
#define KF 32768        /* 256 h * 128 d.  slice s: 16 h x 64 d, kappa = h_loc*64 + d_loc */
#define LN_EPS 1e-5f
#define KSPLIT 32
#define KSL 1024
#define BM 128
#define BN 256
#define BK 32

typedef __attribute__((ext_vector_type(8))) short short8;
typedef __attribute__((ext_vector_type(4))) float float4_t;
typedef __attribute__((ext_vector_type(4))) float vf4;

__device__ __forceinline__ unsigned short f2bf(float f) {
    unsigned int u = __builtin_bit_cast(unsigned int, f);
    u += 0x7fffu + ((u >> 16) & 1u);   // RNE
    return (unsigned short)(u >> 16);
}
__device__ __forceinline__ unsigned int pk2(float lo, float hi) {
    return (unsigned int)f2bf(lo) | ((unsigned int)f2bf(hi) << 16);
}
__device__ __forceinline__ void gl2lds16(const void* g, void* l) {
    __builtin_amdgcn_global_load_lds(
        (const __attribute__((address_space(1))) unsigned int*)g,
        (__attribute__((address_space(3))) unsigned int*)l, 16, 0, 0);
}

// ---------------------------------------------------------------------------
// prep_b: GwT[j][kappa_glob] = bf16(g[d] * Wh[h*128+d][j]) where
//   kappa_glob = s*1024 + h_loc*64 + d_loc,  s = (h>>4)*2 + (d>>6).
// 16B-chunk swizzle within each 32-k window: pos = chunk ^ ((j>>1)&3).
// Cbeta[j] += beta[d]*Wh[k][j] accumulated via atomics.
// ---------------------------------------------------------------------------
__global__ void prep_b(const float* __restrict__ Wh, const float* __restrict__ g,
                       const float* __restrict__ beta,
                       unsigned short* __restrict__ GwT, float* __restrict__ Cbeta) {
    __shared__ unsigned short tile[64][65];
    __shared__ float cred[4][64];
    int kb = blockIdx.x, jb = blockIdx.y;
    int t = threadIdx.x, c = t & 63, r4 = t >> 6;
    int kap0 = kb * 64;
    int s = kb >> 4, h_loc = kb & 15;
    int h = (s >> 1) * 16 + h_loc;
    int dbase = (s & 1) * 64;
    float cb = 0.f;
    for (int rr = r4; rr < 64; rr += 4) {
        int d = dbase + rr;
        float w = Wh[(long)(h * 128 + d) * 256 + jb * 64 + c];
        tile[rr][c] = f2bf(g[d] * w);
        cb += beta[d] * w;
    }
    cred[r4][c] = cb;
    __syncthreads();
    if (r4 == 0)
        atomicAdd(&Cbeta[jb * 64 + c], cred[0][c] + cred[1][c] + cred[2][c] + cred[3][c]);
    for (int rr = r4; rr < 64; rr += 4) {
        int jrow = jb * 64 + rr;
        int c2 = c & 31;
        int pos = ((c2 >> 3) ^ ((jrow >> 1) & 3)) & 3;
        GwT[(long)jrow * KF + kap0 + (c & 32) + pos * 8 + (c & 7)] = tile[c][rr];
    }
}

// ---------------------------------------------------------------------------
// trans_wb: Win,bin [d=128][h=256] f32 -> WinT,binT [h=256][d=128] f32
// ---------------------------------------------------------------------------
__global__ void trans_wb(const float* __restrict__ Win, const float* __restrict__ bin,
                         float* __restrict__ WinT, float* __restrict__ binT) {
    __shared__ float tile[64][65];
    const float* src = blockIdx.z ? bin : Win;
    float* dst = blockIdx.z ? binT : WinT;
    int db = blockIdx.x, hb = blockIdx.y;
    int t = threadIdx.x, c = t & 63, r4 = t >> 6;
    for (int rr = r4; rr < 64; rr += 4)
        tile[rr][c] = src[(db * 64 + rr) * 256 + hb * 64 + c];
    __syncthreads();
    for (int rr = r4; rr < 64; rr += 4)
        dst[(hb * 64 + rr) * 128 + db * 64 + c] = tile[c][rr];
}

// ---------------------------------------------------------------------------
// stats: per (n,h) from FP32 a:  rs = rsqrt(var_d(x)+eps), mrs = -mu*rs.
// rsm layout [n][h] float2 (coalesced writes).
// ---------------------------------------------------------------------------
__global__ void stats(const float* __restrict__ arr, const float* __restrict__ Win,
                      const float* __restrict__ bin, float* __restrict__ rsm) {
    __shared__ float a_s[4][128];
    int t = threadIdx.x;
    int n0 = blockIdx.x * 4;
    for (int i = t; i < 512; i += 256) a_s[i >> 7][i & 127] = arr[n0 * 128 + i];
    __syncthreads();
    float sum[4] = {}, ssq[4] = {};
    for (int d = 0; d < 128; ++d) {
        float w = Win[d * 256 + t], bb = bin[d * 256 + t];
#pragma unroll
        for (int q = 0; q < 4; ++q) {
            float x = fmaxf(fmaf(a_s[q][d], w, bb), 0.f);
            sum[q] += x; ssq[q] += x * x;
        }
    }
    float2* rsm2 = (float2*)rsm;
#pragma unroll
    for (int q = 0; q < 4; ++q) {
        float mu = sum[q] * (1.f / 128.f);
        float var = fmaxf(ssq[q] * (1.f / 128.f) - mu * mu, 0.f);
        float rs = rsqrtf(var + LN_EPS);
        rsm2[(long)(n0 + q) * 256 + t] = make_float2(rs, -mu * rs);
    }
}

// ---------------------------------------------------------------------------
// gemm_f: fused z-gen + GEMM, z computed in FP32 from registers (a fp32).
//   Cp[s][n][j] = sum_{kappa in slice s} z[n,kappa] * GwT[j][kappa]
//   BM=128, BN=256, BK=32, 4 waves, wave-tile 64m x 128n.
//   Slice = 16 h x 64 d; 2-phase loop over d-halves keeps a-regs at 32 VGPRs.
// ---------------------------------------------------------------------------
__global__ __launch_bounds__(256, 2) void gemm_f(
        const float* __restrict__ arr, const float* __restrict__ WinT,
        const float* __restrict__ binT, const float* __restrict__ rsm,
        const unsigned short* __restrict__ GwT, float* __restrict__ Cp) {
    __shared__ float wi_s[16 * 64];            // [hl][64 d] f32, 4KB
    __shared__ float bi_s[16 * 64];            // 4KB
    __shared__ float rs_s[128 * 17 * 2];       // [m][hl(pad17)][{rs,mrs}], 17.4KB
    __shared__ unsigned short Bs[BN * BK];     // [j][32 k] bf16, swizzled, 16KB

    int bid = blockIdx.x;
    int mt = bid >> 5;          // 0..15
    int s = bid & 31;           // slice; blocks sharing s land on one XCD (bid%8==s%8)
    int m0 = mt * BM;
    int hs0 = (s >> 1) * 16;
    int ds = s & 1;
    int t = threadIdx.x, lane = t & 63, wave = t >> 6;
    int fr = lane & 15, kg = lane >> 4;
    int wm = (wave & 1) * 64, wn = (wave >> 1) * 128;

    // ---- preamble staging ----
    gl2lds16(WinT + (hs0 + (t >> 4)) * 128 + ds * 64 + (t & 15) * 4, &wi_s[t * 4]);
    gl2lds16(binT + (hs0 + (t >> 4)) * 128 + ds * 64 + (t & 15) * 4, &bi_s[t * 4]);
    const float2* rsm2 = (const float2*)rsm;
#pragma unroll
    for (int i = 0; i < 8; ++i) {
        int ci = t + i * 256;               // 0..2047
        int m = ci >> 4, hl = ci & 15;
        float2 rv = rsm2[(long)(m0 + m) * 256 + hs0 + hl];
        *(float2*)&rs_s[(m * 17 + hl) * 2] = rv;
    }

    float4_t acc[4][8] = {};
    const unsigned short* Bg = GwT + (long)s * KSL;

    for (int dh = 0; dh < 2; ++dh) {
        // fp32 a for this d-half: 4 rows x 8 d per lane
        vf4 a0[4], a1[4];
#pragma unroll
        for (int mi = 0; mi < 4; ++mi) {
            const float* ap = arr + (long)(m0 + wm + mi * 16 + fr) * 128
                              + ds * 64 + dh * 32 + kg * 8;
            a0[mi] = *(const vf4*)ap;
            a1[mi] = *(const vf4*)(ap + 4);
        }
        for (int hl = 0; hl < 16; ++hl) {
            int w = hl * 2 + dh;            // 32-k window index within slice
            __syncthreads();                // prev MFMA reads done; preamble visible
#pragma unroll
            for (int i = 0; i < 4; ++i) {
                int ci = t + i * 256;
                gl2lds16(Bg + (long)(ci >> 2) * KF + w * 32 + (ci & 3) * 8,
                         &Bs[ci * 8]);
            }
            // ---- A-frag z-gen (fp32, overlaps B DMA) ----
            vf4 w0 = *(const vf4*)&wi_s[hl * 64 + dh * 32 + kg * 8];
            vf4 w1 = *(const vf4*)&wi_s[hl * 64 + dh * 32 + kg * 8 + 4];
            vf4 b0 = *(const vf4*)&bi_s[hl * 64 + dh * 32 + kg * 8];
            vf4 b1 = *(const vf4*)&bi_s[hl * 64 + dh * 32 + kg * 8 + 4];
            short8 af[4];
#pragma unroll
            for (int mi = 0; mi < 4; ++mi) {
                float2 rv = *(const float2*)&rs_s[((wm + mi * 16 + fr) * 17 + hl) * 2];
                float z[8];
#pragma unroll
                for (int j = 0; j < 4; ++j) {
                    float x = fmaxf(fmaf(a0[mi][j], w0[j], b0[j]), 0.f);
                    z[j] = fmaf(x, rv.x, rv.y);
                    float x2 = fmaxf(fmaf(a1[mi][j], w1[j], b1[j]), 0.f);
                    z[4 + j] = fmaf(x2, rv.x, rv.y);
                }
                union { short8 v; unsigned int u[4]; } pa;
#pragma unroll
                for (int p = 0; p < 4; ++p) pa.u[p] = pk2(z[2 * p], z[2 * p + 1]);
                af[mi] = pa.v;
            }
            __syncthreads();                // Bs ready (barrier drains vmcnt)
#pragma unroll
            for (int ni = 0; ni < 8; ++ni) {
                int n = wn + ni * 16 + fr;
                int bc = kg ^ ((n >> 1) & 3);
                short8 bf = *(const short8*)&Bs[n * 32 + bc * 8];
#pragma unroll
                for (int mi = 0; mi < 4; ++mi)
                    acc[mi][ni] = __builtin_amdgcn_mfma_f32_16x16x32_bf16(
                        af[mi], bf, acc[mi][ni], 0, 0, 0);
            }
        }
    }

    // epilogue: col = lane&15 -> n, row = kg*4 + r -> m
    float* Cb = Cp + (long)s * NB * 256;
    int rb = kg * 4;
#pragma unroll
    for (int mi = 0; mi < 4; ++mi) {
#pragma unroll
        for (int ni = 0; ni < 8; ++ni) {
            int n = wn + ni * 16 + fr;
#pragma unroll
            for (int r = 0; r < 4; ++r) {
                int m = m0 + wm + mi * 16 + rb + r;
                Cb[(long)m * 256 + n] = acc[mi][ni][r];
            }
        }
    }
}

// ---------------------------------------------------------------------------
// finale: out[n] = bo + sum_j Wo[j]*relu(bh[j] + Cbeta[j] + sum_s Cp[s][n][j])
// ---------------------------------------------------------------------------
__global__ void finale(const float* __restrict__ Cp, const float* __restrict__ Cbeta,
                       const float* __restrict__ bh, const float* __restrict__ Wo,
                       const float* __restrict__ bo, float* __restrict__ out) {
    __shared__ float red[4];
    int n = blockIdx.x, t = threadIdx.x;
    int lane = t & 63, wave = t >> 6;
    float ssum = bh[t] + Cbeta[t];
    for (int sl = 0; sl < KSPLIT; ++sl)
        ssum += Cp[(long)sl * NB * 256 + (long)n * 256 + t];
    float v = fmaxf(ssum, 0.f) * Wo[t];
#pragma unroll
    for (int o = 32; o; o >>= 1) v += __shfl_down(v, o);
    if (lane == 0) red[wave] = v;
    __syncthreads();
    if (t == 0) out[n] = red[0] + red[1] + red[2] + red[3] + bo[0];
}

extern "C" void kernel_launch(void* const* d_in, const int* in_sizes, int n_in,
                              void* d_out, int out_size, void* d_ws, size_t ws_size,
                              hipStream_t stream) {
    const float* arr  = (const float*)d_in[0];
    const float* Win  = (const float*)d_in[1];
    const float* bin  = (const float*)d_in[2];
    const float* ln_g = (const float*)d_in[7];
    const float* ln_b = (const float*)d_in[8];
    const float* Wh   = (const float*)d_in[9];
    const float* bh   = (const float*)d_in[10];
    const float* Wo   = (const float*)d_in[11];
    const float* bo   = (const float*)d_in[12];
    float* out = (float*)d_out;

    char* ws = (char*)d_ws;
    unsigned short* GwT  = (unsigned short*)(ws);                    // 16 MB
    float*          Cp   = (float*)(ws + 16777216ull);               // 64 MB
    float*          rsm  = (float*)(ws + 83886080ull);               // 4 MB
    float*          WinT = (float*)(ws + 88080384ull);               // 128 KB
    float*          binT = (float*)(ws + 88211456ull);               // 128 KB
    float*          Cbeta= (float*)(ws + 88342528ull);               // 1 KB

    hipMemsetAsync(Cbeta, 0, 256 * sizeof(float), stream);
    hipLaunchKernelGGL(prep_b, dim3(512, 4), dim3(256), 0, stream, Wh, ln_g, ln_b, GwT, Cbeta);
    hipLaunchKernelGGL(trans_wb, dim3(2, 4, 2), dim3(256), 0, stream, Win, bin, WinT, binT);
    hipLaunchKernelGGL(stats, dim3(512), dim3(256), 0, stream, arr, Win, bin, rsm);
    hipLaunchKernelGGL(gemm_f, dim3(512), dim3(256), 0, stream, arr, WinT, binT, rsm, GwT, Cp);
    hipLaunchKernelGGL(finale, dim3(NB), dim3(256), 0, stream, Cp, Cbeta, bh, Wo, bo, out);
}